// Round 7
// baseline (1323.621 us; speedup 1.0000x reference)
//
#include <hip/hip_runtime.h>
#include <cstdint>

#define NB 8
#define CIN 1024
#define HDIM 50
#define WDIM 50
#define COUT 512
#define NA 9
#define NANCH (HDIM*WDIM*NA)   /* 22500 */
#define PRE_N 2000
#define POST_N 100

typedef __attribute__((ext_vector_type(8))) short bf16x8;
typedef __attribute__((ext_vector_type(4))) float f32x4;
typedef __attribute__((ext_vector_type(16))) float f32x16;
typedef __attribute__((ext_vector_type(8))) unsigned short ushort8v;

// ---------------- workspace layout (bytes) ----------------
// t planes (bf16 hi/lo) in proj-A-frag order: [pxblk157][cchunk16][mf8][q4][pxl16][j8]
constexpr size_t TPLANE    = 20578304;                   // 157*16*4096 shorts * 2B
constexpr size_t OFF_TPH   = 0;
constexpr size_t OFF_TPL   = OFF_TPH + TPLANE;           // 20,578,304
constexpr size_t OFF_BOXES = 41156608;                   // 8*22500*4 f32
constexpr size_t OFF_MS    = OFF_BOXES + 2880000;        // 8*22500 f32
constexpr size_t OFF_KEYS  = OFF_MS + 720000;            // 8*22500 u64
constexpr size_t OFF_TBOX  = OFF_KEYS + 1440000;         // 8*2000*4 f32
constexpr size_t OFF_TS    = OFF_TBOX + 256000;          // 8*2000 f32
constexpr size_t OFF_SUP   = OFF_TS + 64000;             // 8*2000*32 u64
constexpr size_t OFF_KEEP  = OFF_SUP + 4096000;          // 8*64 u32
// feature planes: [b8][cic64][rr52][lk2][cc52][ci8] bf16 (rr/cc include zero halo)
constexpr size_t PPLANE    = 44318720;                   // 44,302,336 used + 16 KB slack
constexpr size_t OFF_PH    = 50614656;
constexpr size_t OFF_PL    = OFF_PH + PPLANE;
// weight planes: [cot8][cic64][tap9][lk2][co64][ci8] bf16  (tap = kh*3+kw -> kh chunks contiguous)
constexpr size_t WPLANE    = 9437184;
constexpr size_t OFF_WH    = OFF_PL + PPLANE;
constexpr size_t OFF_WL    = OFF_WH + WPLANE;
// end ~158.1 MB

__device__ __forceinline__ void split2bf16(float v, unsigned short &hi, unsigned short &lo) {
    unsigned int u = __float_as_uint(v);
    unsigned int r = u + 0x7FFFu + ((u >> 16) & 1u);
    hi = (unsigned short)(r >> 16);
    float hf = __uint_as_float(((unsigned int)hi) << 16);
    float lf = v - hf;
    unsigned int u2 = __float_as_uint(lf);
    unsigned int r2 = u2 + 0x7FFFu + ((u2 >> 16) & 1u);
    lo = (unsigned short)(r2 >> 16);
}

__device__ __forceinline__ void gl_lds(const unsigned short* g, unsigned short* l) {
    __builtin_amdgcn_global_load_lds(
        (const __attribute__((address_space(1))) unsigned int*)(const void*)g,
        (__attribute__((address_space(3))) unsigned int*)(void*)l,
        16, 0, 0);
}

// ---------------- preprocess: feature -> hi/lo bf16 planes [b][cic][rr][lk][cc][8] ----------------
__global__ __launch_bounds__(256) void prep_feat(const float* __restrict__ f,
                                                 unsigned short* __restrict__ Ph,
                                                 unsigned short* __restrict__ Pl) {
    int id = blockIdx.x * 256 + threadIdx.x;
    int cc = id % 52; int r = id / 52;
    int rr = r % 52;  r /= 52;
    int cic = r % 64; int b = r / 64;
    int h = rr - 1, w = cc - 1;
    bool inb = (h >= 0 && h < HDIM && w >= 0 && w < WDIM);
    ushort8v hv0, lv0, hv1, lv1;
#pragma unroll
    for (int j = 0; j < 16; ++j) {
        float v = 0.f;
        if (inb) v = f[(((size_t)b * CIN + cic * 16 + j) * HDIM + h) * WDIM + w];
        unsigned short hi, lo;
        split2bf16(v, hi, lo);
        if (j < 8) { hv0[j] = hi; lv0[j] = lo; }
        else       { hv1[j - 8] = hi; lv1[j - 8] = lo; }
    }
    size_t rowb = (size_t)((b * 64 + cic) * 52 + rr) * 832;
    *(ushort8v*)&Ph[rowb + cc * 8]       = hv0;   // lk=0
    *(ushort8v*)&Ph[rowb + 416 + cc * 8] = hv1;   // lk=1
    *(ushort8v*)&Pl[rowb + cc * 8]       = lv0;
    *(ushort8v*)&Pl[rowb + 416 + cc * 8] = lv1;
}

// ---------------- preprocess: W1 -> hi/lo planes [cot8][cic][tap][lk][co64][8] ----------------
// thread = one (cot,cic,co). grid: 8*64*64/256 = 128
__global__ __launch_bounds__(256) void prep_w(const float* __restrict__ W1,
                                              unsigned short* __restrict__ Wh,
                                              unsigned short* __restrict__ Wl) {
    int id = blockIdx.x * 256 + threadIdx.x;
    int co = id % 64; int r = id / 64;
    int cic = r % 64; int cot = r / 64;
    int cog = cot * 64 + co;
    const float* src = W1 + ((size_t)cog * CIN + cic * 16) * 9;   // 144 consecutive floats
    float v[144];
#pragma unroll
    for (int i = 0; i < 36; ++i) {
        float4 x = ((const float4*)src)[i];
        v[i * 4 + 0] = x.x; v[i * 4 + 1] = x.y; v[i * 4 + 2] = x.z; v[i * 4 + 3] = x.w;
    }
#pragma unroll
    for (int tap = 0; tap < 9; ++tap) {
        ushort8v hv0, lv0, hv1, lv1;
#pragma unroll
        for (int j = 0; j < 16; ++j) {
            unsigned short hi, lo;
            split2bf16(v[j * 9 + tap], hi, lo);
            if (j < 8) { hv0[j] = hi; lv0[j] = lo; }
            else       { hv1[j - 8] = hi; lv1[j - 8] = lo; }
        }
        size_t base = ((((size_t)(cot * 64 + cic)) * 9 + tap) * 2) * 512;  // shorts
        *(ushort8v*)&Wh[base + co * 8]       = hv0;   // lk=0
        *(ushort8v*)&Wh[base + 512 + co * 8] = hv1;   // lk=1
        *(ushort8v*)&Wl[base + co * 8]       = lv0;
        *(ushort8v*)&Wl[base + 512 + co * 8] = lv1;
    }
}

// ---------------- conv 3x3: split-bf16 MFMA 32x32x16, kh-chunked double-buffered units ----------------
// grid: 832 = b(8) x mt(13) x cot(8). Block: 4 rows x 64 cols(M) x 64 co(N).
// Unit = (cic, kh): A slice = 4 rows starting rr=r0+kh, B chunk = 3 taps. 192 units, dbuf, 1 barrier each.
__global__ __launch_bounds__(256, 3) void conv_mfma(const unsigned short* __restrict__ FPh,
                                                    const unsigned short* __restrict__ FPl,
                                                    const unsigned short* __restrict__ WPh,
                                                    const unsigned short* __restrict__ WPl,
                                                    const float* __restrict__ b1,
                                                    unsigned short* __restrict__ Tph,
                                                    unsigned short* __restrict__ Tpl) {
    __shared__ unsigned short sA[2][2][3584];   // [buf][h/l][4 rows x 832sh = 3328 + slack] = 28,672 B
    __shared__ unsigned short sB[2][2][3072];   // [buf][h/l][kw3][lk2][co64][8]            = 24,576 B
    // total 53,248 B -> 3 blocks/CU

    int blk = blockIdx.x;
    int cot = blk & 7;
    int mt  = (blk >> 3) % 13;
    int b   = blk / 104;
    int co0 = cot * 64;
    int r0  = mt * 4;

    int t = threadIdx.x, wv = t >> 6, ln = t & 63;
    int lm = ln & 31, lk = ln >> 5;

    f32x16 acc[2][2];
#pragma unroll
    for (int jm = 0; jm < 2; ++jm)
#pragma unroll
        for (int jn = 0; jn < 2; ++jn)
#pragma unroll
            for (int rg = 0; rg < 16; ++rg) acc[jm][jn][rg] = 0.f;

    // ---- prologue: stage unit 0 into buf 0 ----
    {
        const unsigned short* aH = FPh + (size_t)((b * 64 + 0) * 52 + r0 + 0) * 832;
        const unsigned short* aL = FPl + (size_t)((b * 64 + 0) * 52 + r0 + 0) * 832;
        const unsigned short* wH = WPh + (size_t)(cot * 64 + 0) * 9216 + 0 * 3072;
        const unsigned short* wL = WPl + (size_t)(cot * 64 + 0) * 9216 + 0 * 3072;
        if (wv == 0) {
#pragma unroll
            for (int s = 0; s < 7; ++s) gl_lds(aH + s * 512 + ln * 8, &sA[0][0][s * 512]);
        } else if (wv == 1) {
#pragma unroll
            for (int s = 0; s < 7; ++s) gl_lds(aL + s * 512 + ln * 8, &sA[0][1][s * 512]);
        } else if (wv == 2) {
#pragma unroll
            for (int s = 0; s < 6; ++s) gl_lds(wH + s * 512 + ln * 8, &sB[0][0][s * 512]);
        } else {
#pragma unroll
            for (int s = 0; s < 6; ++s) gl_lds(wL + s * 512 + ln * 8, &sB[0][1][s * 512]);
        }
    }

#pragma unroll 1
    for (int u = 0; u < 192; ++u) {
        int p = u & 1;
        __syncthreads();   // drains: staging of unit u (vmcnt) + prev compute reads (lgkm)

        // stage unit u+1 into buf 1-p (in flight during compute of u)
        if (u + 1 < 192) {
            int nu = u + 1;
            int ncic = nu / 3, nkh = nu - ncic * 3;
            const unsigned short* aH = FPh + (size_t)((b * 64 + ncic) * 52 + r0 + nkh) * 832;
            const unsigned short* aL = FPl + (size_t)((b * 64 + ncic) * 52 + r0 + nkh) * 832;
            const unsigned short* wH = WPh + (size_t)(cot * 64 + ncic) * 9216 + nkh * 3072;
            const unsigned short* wL = WPl + (size_t)(cot * 64 + ncic) * 9216 + nkh * 3072;
            int q = 1 - p;
            if (wv == 0) {
#pragma unroll
                for (int s = 0; s < 7; ++s) gl_lds(aH + s * 512 + ln * 8, &sA[q][0][s * 512]);
            } else if (wv == 1) {
#pragma unroll
                for (int s = 0; s < 7; ++s) gl_lds(aL + s * 512 + ln * 8, &sA[q][1][s * 512]);
            } else if (wv == 2) {
#pragma unroll
                for (int s = 0; s < 6; ++s) gl_lds(wH + s * 512 + ln * 8, &sB[q][0][s * 512]);
            } else {
#pragma unroll
                for (int s = 0; s < 6; ++s) gl_lds(wL + s * 512 + ln * 8, &sB[q][1][s * 512]);
            }
        }

        // compute unit u from buf p: wave wv reads A slice row wv (input row r0+kh-1+wv)
#pragma unroll
        for (int kw = 0; kw < 3; ++kw) {
            bf16x8 a[2][2], bb[2][2];
#pragma unroll
            for (int jm = 0; jm < 2; ++jm) {
                int cc = jm * 32 + lm + kw;
                if (cc > 51) cc = 51;              // pad lanes (M>=50): clamp, result discarded
                int ad = wv * 832 + lk * 416 + cc * 8;
                a[jm][0] = *(const bf16x8*)&sA[p][0][ad];
                a[jm][1] = *(const bf16x8*)&sA[p][1][ad];
            }
#pragma unroll
            for (int jn = 0; jn < 2; ++jn) {
                int bd = ((kw * 2 + lk) * 64 + jn * 32 + lm) * 8;
                bb[jn][0] = *(const bf16x8*)&sB[p][0][bd];
                bb[jn][1] = *(const bf16x8*)&sB[p][1][bd];
            }
#pragma unroll
            for (int jm = 0; jm < 2; ++jm)
#pragma unroll
                for (int jn = 0; jn < 2; ++jn) {
                    acc[jm][jn] = __builtin_amdgcn_mfma_f32_32x32x16_bf16(a[jm][0], bb[jn][0], acc[jm][jn], 0, 0, 0);
                    acc[jm][jn] = __builtin_amdgcn_mfma_f32_32x32x16_bf16(a[jm][0], bb[jn][1], acc[jm][jn], 0, 0, 0);
                    acc[jm][jn] = __builtin_amdgcn_mfma_f32_32x32x16_bf16(a[jm][1], bb[jn][0], acc[jm][jn], 0, 0, 0);
                }
        }
    }

    // epilogue: bias+relu, split to bf16 hi/lo, store in proj-A-frag plane order
    int h = r0 + wv;
    if (h >= HDIM) return;
#pragma unroll
    for (int jn = 0; jn < 2; ++jn) {
        int co = co0 + jn * 32 + lm;
        float bv = b1[co];
#pragma unroll
        for (int jm = 0; jm < 2; ++jm) {
#pragma unroll
            for (int rg = 0; rg < 16; ++rg) {
                int w = jm * 32 + (rg & 3) + 8 * (rg >> 2) + 4 * lk;
                if (w < WDIM) {
                    float v = fmaxf(acc[jm][jn][rg] + bv, 0.f);
                    unsigned short hi, lo;
                    split2bf16(v, hi, lo);
                    int px = b * 2500 + h * 50 + w;
                    size_t sa = (((((size_t)(px >> 7) * 16 + (co >> 5)) * 8 + ((px >> 4) & 7)) * 4
                                  + ((co >> 3) & 3)) * 16 + (px & 15)) * 8 + (co & 7);
                    Tph[sa] = hi;
                    Tpl[sa] = lo;
                }
            }
        }
    }
}

// ---------------- projection (MFMA, planes staged via gl_lds) + decode + key build ----------------
__global__ __launch_bounds__(256) void proj_decode_mfma(const unsigned short* __restrict__ Tph,
                                                        const unsigned short* __restrict__ Tpl,
                                                        const float* __restrict__ W2,
                                                        const float* __restrict__ b2,
                                                        const float* __restrict__ W3,
                                                        const float* __restrict__ b3,
                                                        float* __restrict__ boxes,
                                                        float* __restrict__ mscores,
                                                        unsigned long long* __restrict__ keys) {
    __shared__ unsigned short sTh[4096], sTl[4096];
    __shared__ unsigned short sWh[1536], sWl[1536];
    __shared__ float pout[128 * 46];

    int blk = blockIdx.x;
    int px0 = blk * 128;
    int t = threadIdx.x, wv = t >> 6, ln = t & 63;
    int lm = ln & 15, q = ln >> 4;

    f32x4 acc[2][3];
#pragma unroll
    for (int jm = 0; jm < 2; ++jm)
#pragma unroll
        for (int nf = 0; nf < 3; ++nf) acc[jm][nf] = (f32x4){0.f, 0.f, 0.f, 0.f};

#pragma unroll 1
    for (int cc16 = 0; cc16 < 16; ++cc16) {
        __syncthreads();
        size_t base = ((size_t)blk * 16 + cc16) * 4096;
        if (wv == 0) {
#pragma unroll
            for (int s = 0; s < 4; ++s) gl_lds(Tph + base + s * 512 + ln * 8, &sTh[s * 512]);
        } else if (wv == 1) {
#pragma unroll
            for (int s = 4; s < 8; ++s) gl_lds(Tph + base + s * 512 + ln * 8, &sTh[s * 512]);
        } else if (wv == 2) {
#pragma unroll
            for (int s = 0; s < 4; ++s) gl_lds(Tpl + base + s * 512 + ln * 8, &sTl[s * 512]);
        } else {
#pragma unroll
            for (int s = 4; s < 8; ++s) gl_lds(Tpl + base + s * 512 + ln * 8, &sTl[s * 512]);
        }
        int c0 = cc16 * 32;
        for (int idx = t; idx < 1536; idx += 256) {
            int o = idx >> 5, ci = idx & 31;
            float v = 0.f;
            if (o < 36) v = W2[o * 512 + c0 + ci];
            else if (o < 45) v = W3[(o - 36) * 512 + c0 + ci];
            unsigned short hi, lo;
            split2bf16(v, hi, lo);
            int ad = (((o >> 4) * 4 + (ci >> 3)) * 16 + (o & 15)) * 8 + (ci & 7);
            sWh[ad] = hi; sWl[ad] = lo;
        }
        __syncthreads();

        bf16x8 a[2][2], bb[3][2];
#pragma unroll
        for (int jm = 0; jm < 2; ++jm) {
            int mf = wv * 2 + jm;
            int ad = ((mf * 4 + q) * 16 + lm) * 8;
            a[jm][0] = *(const bf16x8*)&sTh[ad];
            a[jm][1] = *(const bf16x8*)&sTl[ad];
        }
#pragma unroll
        for (int nf = 0; nf < 3; ++nf) {
            int ad = ((nf * 4 + q) * 16 + lm) * 8;
            bb[nf][0] = *(const bf16x8*)&sWh[ad];
            bb[nf][1] = *(const bf16x8*)&sWl[ad];
        }
#pragma unroll
        for (int jm = 0; jm < 2; ++jm)
#pragma unroll
            for (int nf = 0; nf < 3; ++nf) {
                acc[jm][nf] = __builtin_amdgcn_mfma_f32_16x16x32_bf16(a[jm][0], bb[nf][0], acc[jm][nf], 0, 0, 0);
                acc[jm][nf] = __builtin_amdgcn_mfma_f32_16x16x32_bf16(a[jm][0], bb[nf][1], acc[jm][nf], 0, 0, 0);
                acc[jm][nf] = __builtin_amdgcn_mfma_f32_16x16x32_bf16(a[jm][1], bb[nf][0], acc[jm][nf], 0, 0, 0);
            }
    }
    __syncthreads();
#pragma unroll
    for (int jm = 0; jm < 2; ++jm)
#pragma unroll
        for (int nf = 0; nf < 3; ++nf) {
            int o = nf * 16 + lm;
            if (o < 45) {
                float bias = (o < 36) ? b2[o] : b3[o - 36];
#pragma unroll
                for (int rg = 0; rg < 4; ++rg) {
                    int pxl = (wv * 2 + jm) * 16 + q * 4 + rg;
                    pout[pxl * 46 + o] = acc[jm][nf][rg] + bias;
                }
            }
        }
    __syncthreads();

    const float AW[9] = {90.50966799187809f, 128.0f, 181.01933598375618f,
                         181.01933598375618f, 256.0f, 362.03867196751236f,
                         362.03867196751236f, 512.0f, 724.0773439350247f};
    const float AH[9] = {181.01933598375618f, 128.0f, 90.50966799187809f,
                         362.03867196751236f, 256.0f, 181.01933598375618f,
                         724.0773439350247f, 512.0f, 362.03867196751236f};
    const float CLIPV = 4.135166556742356f;
    const float IMG = 1600.0f;

    for (int it = t; it < 128 * 9; it += 256) {
        int pxl = it / 9, a = it - pxl * 9;
        int pxg = px0 + pxl;
        if (pxg >= 20000) continue;
        int b = pxg / 2500, rem = pxg % 2500;
        int h = rem / 50, w = rem % 50;

        float tx = pout[pxl * 46 + a * 4 + 0];
        float ty = pout[pxl * 46 + a * 4 + 1];
        float tw = pout[pxl * 46 + a * 4 + 2];
        float th = pout[pxl * 46 + a * 4 + 3];
        float lg = pout[pxl * 46 + 36 + a];

        float s = 1.0f / (1.0f + expf(-lg));

        float cx = ((float)w + 0.5f) * 32.0f;
        float cy = ((float)h + 0.5f) * 32.0f;
        float x1a = cx - 0.5f * AW[a];
        float x2a = cx + 0.5f * AW[a];
        float y1a = cy - 0.5f * AH[a];
        float y2a = cy + 0.5f * AH[a];
        float waf = x2a - x1a;
        float haf = y2a - y1a;
        float cxa = x1a + 0.5f * waf;
        float cya = y1a + 0.5f * haf;

        float twc = tw < CLIPV ? tw : CLIPV;
        float thc = th < CLIPV ? th : CLIPV;
        float pxc = tx * waf + cxa;
        float pyc = ty * haf + cya;
        float pw  = expf(twc) * waf;
        float ph  = expf(thc) * haf;

        float x1 = pxc - 0.5f * pw;
        float y1 = pyc - 0.5f * ph;
        float x2 = pxc + 0.5f * pw;
        float y2 = pyc + 0.5f * ph;
        x1 = fminf(fmaxf(x1, 0.f), IMG);
        y1 = fminf(fmaxf(y1, 0.f), IMG);
        x2 = fminf(fmaxf(x2, 0.f), IMG);
        y2 = fminf(fmaxf(y2, 0.f), IMG);

        float bw = x2 - x1, bh = y2 - y1;
        bool valid = (s >= 0.1f) && (bw > 16.0f) && (bh > 16.0f);
        float m = valid ? s : -1.0f;

        int idx = (h * WDIM + w) * NA + a;
        size_t gi = (size_t)b * NANCH + idx;
        ((float4*)boxes)[gi] = make_float4(x1, y1, x2, y2);
        mscores[gi] = m;
        unsigned int u = __float_as_uint(m);
        unsigned int k32 = (u & 0x80000000u) ? ~u : (u | 0x80000000u);
        keys[gi] = ((unsigned long long)k32 << 15) | (unsigned long long)(32767 - idx);
    }
}

// ---------------- exact stable top-2000 (47-bit radix select, 4 passes + bitonic), 1024 thr ----------------
__global__ __launch_bounds__(1024) void select_sort_kernel(const unsigned long long* __restrict__ keys,
                                                           const float* __restrict__ boxes,
                                                           const float* __restrict__ mscores,
                                                           float* __restrict__ top_boxes,
                                                           float* __restrict__ top_s) {
    int b = blockIdx.x;
    int t = threadIdx.x;
    const unsigned long long* kb = keys + (size_t)b * NANCH;

    __shared__ unsigned int hist[4096];
    __shared__ unsigned int gs[1024];
    __shared__ int s_chosen, s_rnew;
    __shared__ unsigned int s_cnt;
    __shared__ unsigned long long skeys[2048];

    const int widths[4] = {12, 12, 12, 11};
    unsigned long long prefix = 0;
    int bitsdone = 0;
    int r = PRE_N;

    for (int p = 0; p < 4; ++p) {
        int width = widths[p];
        int bins = 1 << width;
        int shift = 47 - bitsdone - width;
        for (int i = t; i < bins; i += 1024) hist[i] = 0;
        __syncthreads();
        for (int i = t; i < NANCH; i += 1024) {
            unsigned long long k = kb[i];
            bool ok = (k >> (47 - bitsdone)) == prefix;
            if (ok) atomicAdd(&hist[(unsigned)((k >> shift) & (unsigned long long)(bins - 1))], 1u);
        }
        __syncthreads();
        int G = bins >> 10;
        unsigned int gsum = 0;
        for (int g = 0; g < G; ++g) gsum += hist[t * G + g];
        gs[t] = gsum;
        __syncthreads();
        if (t == 0) {
            int acc = 0, chosen = 0, rnew = 1;
            for (int g = 1023; g >= 0; --g) {
                int sgv = (int)gs[g];
                if (acc + sgv >= r) {
                    for (int d = g * G + G - 1; d >= g * G; --d) {
                        int hv = (int)hist[d];
                        if (acc + hv >= r) { chosen = d; rnew = r - acc; break; }
                        acc += hv;
                    }
                    break;
                }
                acc += sgv;
            }
            s_chosen = chosen;
            s_rnew = rnew;
        }
        __syncthreads();
        prefix = (prefix << width) | (unsigned long long)s_chosen;
        bitsdone += width;
        r = s_rnew;
        __syncthreads();
    }
    unsigned long long Kst = prefix;   // exact rank-2000 key (47-bit)

    if (t == 0) s_cnt = 0;
    __syncthreads();
    for (int i = t; i < NANCH; i += 1024) {
        unsigned long long k = kb[i];
        if (k >= Kst) {
            unsigned int p = atomicAdd(&s_cnt, 1u);
            if (p < 2048) skeys[p] = k;
        }
    }
    __syncthreads();
    unsigned int cnt = s_cnt;
    for (int i = t; i < 2048; i += 1024)
        if (i >= (int)cnt) skeys[i] = 0ull;
    for (int k = 2; k <= 2048; k <<= 1) {
        for (int j = k >> 1; j > 0; j >>= 1) {
            __syncthreads();
            for (int i = t; i < 2048; i += 1024) {
                int l = i ^ j;
                if (l > i) {
                    unsigned long long a = skeys[i], c = skeys[l];
                    bool up = ((i & k) == 0);
                    if (up ? (a < c) : (a > c)) { skeys[i] = c; skeys[l] = a; }
                }
            }
        }
    }
    __syncthreads();
    for (int i = t; i < PRE_N; i += 1024) {
        unsigned long long k = skeys[i];
        unsigned int idx = 32767u - (unsigned int)(k & 32767ull);
        size_t gi = (size_t)b * NANCH + idx;
        top_s[b * PRE_N + i] = mscores[gi];
        ((float4*)top_boxes)[b * PRE_N + i] = ((const float4*)boxes)[gi];
    }
}

// ---------------- IoU suppression bit-matrix ----------------
__global__ __launch_bounds__(256) void sup_kernel(const float* __restrict__ top_boxes,
                                                  unsigned long long* __restrict__ supm) {
    int blk = blockIdx.x;
    int b = blk / 125;
    int chunk = blk % 125;
    int t = threadIdx.x;

    __shared__ float bx1[PRE_N], by1[PRE_N], bx2[PRE_N], by2[PRE_N];
    for (int i = t; i < PRE_N; i += 256) {
        float4 v = ((const float4*)top_boxes)[b * PRE_N + i];
        bx1[i] = v.x; by1[i] = v.y; bx2[i] = v.z; by2[i] = v.w;
    }
    __syncthreads();

    int wave = t >> 6, lane = t & 63;
    for (int rr = 0; rr < 4; ++rr) {
        int i = chunk * 16 + wave * 4 + rr;
        float ax1 = bx1[i], ay1 = by1[i], ax2 = bx2[i], ay2 = by2[i];
        float aarea = (ax2 - ax1) * (ay2 - ay1);
        for (int jw = 0; jw < 32; ++jw) {
            int j = jw * 64 + lane;
            bool sup = false;
            if (j > i && j < PRE_N) {
                float jx1 = bx1[j], jy1 = by1[j], jx2 = bx2[j], jy2 = by2[j];
                float ix1 = fmaxf(ax1, jx1), iy1 = fmaxf(ay1, jy1);
                float ix2 = fminf(ax2, jx2), iy2 = fminf(ay2, jy2);
                float iw = fmaxf(ix2 - ix1, 0.f);
                float ih = fmaxf(iy2 - iy1, 0.f);
                float inter = iw * ih;
                float barea = (jx2 - jx1) * (jy2 - jy1);
                float iou = inter / (aarea + barea - inter + 1e-9f);
                sup = iou > 0.7f;
            }
            unsigned long long m = __ballot(sup);
            if (lane == 0) supm[((size_t)b * PRE_N + i) * 32 + jw] = m;
        }
    }
}

// ---------------- tiled NMS scan ----------------
__global__ __launch_bounds__(64) void nms_scan_kernel(const float* __restrict__ top_s,
                                                      const unsigned long long* __restrict__ supm,
                                                      unsigned int* __restrict__ keepout) {
    int b = blockIdx.x;
    int lane = threadIdx.x;
    unsigned int alive = 0;
    for (int q = 0; q < 32; ++q) {
        int i = lane * 32 + q;
        if (i < PRE_N && top_s[b * PRE_N + i] > 0.f) alive |= (1u << q);
    }
    const unsigned long long* sm = supm + (size_t)b * PRE_N * 32;
    const unsigned int* sup32 = (const unsigned int*)sm;

    for (int tt = 0; tt < 32; ++tt) {
        unsigned int alo = __shfl(alive, 2 * tt);
        unsigned int ahi = __shfl(alive, 2 * tt + 1);
        unsigned long long talive = (unsigned long long)alo | ((unsigned long long)ahi << 32);
        int i_row = tt * 64 + lane;
        unsigned long long rm = (i_row < PRE_N) ? sm[(size_t)i_row * 32 + tt] : 0ull;

        unsigned long long kept = 0, rem = talive;
        while (rem) {
            int j = __builtin_ctzll(rem);
            kept |= (1ull << j);
            unsigned long long rmj = __shfl(rm, j);
            rem &= ~rmj;
            rem &= ~(1ull << j);
        }

        unsigned int oracc = 0;
        unsigned long long kk = kept;
        while (kk) {
            int j0 = __builtin_ctzll(kk); kk &= kk - 1;
            int j1 = -1, j2 = -1, j3 = -1;
            if (kk) { j1 = __builtin_ctzll(kk); kk &= kk - 1; }
            if (kk) { j2 = __builtin_ctzll(kk); kk &= kk - 1; }
            if (kk) { j3 = __builtin_ctzll(kk); kk &= kk - 1; }
            unsigned int v0 = sup32[(size_t)(tt * 64 + j0) * 64 + lane];
            unsigned int v1 = (j1 >= 0) ? sup32[(size_t)(tt * 64 + j1) * 64 + lane] : 0u;
            unsigned int v2 = (j2 >= 0) ? sup32[(size_t)(tt * 64 + j2) * 64 + lane] : 0u;
            unsigned int v3 = (j3 >= 0) ? sup32[(size_t)(tt * 64 + j3) * 64 + lane] : 0u;
            oracc |= v0 | v1 | v2 | v3;
        }
        alive &= ~oracc;
        if (lane == 2 * tt)     alive = (unsigned int)kept;
        if (lane == 2 * tt + 1) alive = (unsigned int)(kept >> 32);
    }
    keepout[b * 64 + lane] = alive;
}

// ---------------- final stable top-100 ----------------
__global__ __launch_bounds__(256) void finalize_kernel(const float* __restrict__ top_boxes,
                                                       const float* __restrict__ top_s,
                                                       const unsigned int* __restrict__ keepin,
                                                       float* __restrict__ out) {
    int b = blockIdx.x;
    int t = threadIdx.x;
    __shared__ unsigned int kw[64];
    __shared__ int wpre[65];
    if (t < 64) kw[t] = keepin[b * 64 + t];
    __syncthreads();
    if (t == 0) {
        int run = 0;
        for (int w = 0; w < 64; ++w) { wpre[w] = run; run += __popc(kw[w]); }
        wpre[64] = run;
    }
    __syncthreads();
    int total = wpre[64];
    float* out_boxes  = out;
    float* out_scores = out + NB * POST_N * 4;
    for (int i = t; i < PRE_N; i += 256) {
        unsigned int w = kw[i >> 5];
        bool kept = (w >> (i & 31)) & 1u;
        int rk = wpre[i >> 5] + __popc(w & ((1u << (i & 31)) - 1u));
        int pos = kept ? rk : total + (i - rk);
        if (pos < POST_N) {
            out_scores[b * POST_N + pos] = kept ? top_s[b * PRE_N + i] : -1.0f;
            ((float4*)out_boxes)[b * POST_N + pos] = ((const float4*)top_boxes)[b * PRE_N + i];
        }
    }
}

// ---------------- launch ----------------
extern "C" void kernel_launch(void* const* d_in, const int* in_sizes, int n_in,
                              void* d_out, int out_size, void* d_ws, size_t ws_size,
                              hipStream_t stream) {
    const float* features = (const float*)d_in[0];
    const float* W1 = (const float*)d_in[1];
    const float* b1 = (const float*)d_in[2];
    const float* W2 = (const float*)d_in[3];
    const float* b2 = (const float*)d_in[4];
    const float* W3 = (const float*)d_in[5];
    const float* b3 = (const float*)d_in[6];
    float* out = (float*)d_out;
    char* ws = (char*)d_ws;

    unsigned short* Tph = (unsigned short*)(ws + OFF_TPH);
    unsigned short* Tpl = (unsigned short*)(ws + OFF_TPL);
    float* boxes   = (float*)(ws + OFF_BOXES);
    float* mscores = (float*)(ws + OFF_MS);
    unsigned long long* keys = (unsigned long long*)(ws + OFF_KEYS);
    float* top_boxes = (float*)(ws + OFF_TBOX);
    float* top_s     = (float*)(ws + OFF_TS);
    unsigned long long* supm = (unsigned long long*)(ws + OFF_SUP);
    unsigned int* keep = (unsigned int*)(ws + OFF_KEEP);
    unsigned short* FPh = (unsigned short*)(ws + OFF_PH);
    unsigned short* FPl = (unsigned short*)(ws + OFF_PL);
    unsigned short* WPh = (unsigned short*)(ws + OFF_WH);
    unsigned short* WPl = (unsigned short*)(ws + OFF_WL);

    prep_feat<<<5408, 256, 0, stream>>>(features, FPh, FPl);
    prep_w<<<128, 256, 0, stream>>>(W1, WPh, WPl);
    conv_mfma<<<832, 256, 0, stream>>>(FPh, FPl, WPh, WPl, b1, Tph, Tpl);
    proj_decode_mfma<<<157, 256, 0, stream>>>(Tph, Tpl, W2, b2, W3, b3, boxes, mscores, keys);
    select_sort_kernel<<<NB, 1024, 0, stream>>>(keys, boxes, mscores, top_boxes, top_s);
    sup_kernel<<<NB * 125, 256, 0, stream>>>(top_boxes, supm);
    nms_scan_kernel<<<NB, 64, 0, stream>>>(top_s, supm, keep);
    finalize_kernel<<<NB, 256, 0, stream>>>(top_boxes, top_s, keep, out);
}

// Round 8
// 1152.086 us; speedup vs baseline: 1.1489x; 1.1489x over previous
//
#include <hip/hip_runtime.h>
#include <cstdint>

#define NB 8
#define CIN 1024
#define HDIM 50
#define WDIM 50
#define COUT 512
#define NA 9
#define NANCH (HDIM*WDIM*NA)   /* 22500 */
#define PRE_N 2000
#define POST_N 100

typedef __attribute__((ext_vector_type(8))) short bf16x8;
typedef __attribute__((ext_vector_type(4))) float f32x4;
typedef __attribute__((ext_vector_type(16))) float f32x16;
typedef __attribute__((ext_vector_type(8))) unsigned short ushort8v;

// ---------------- workspace layout (bytes) ----------------
// t planes (bf16 hi/lo) in proj-A-frag order: [pxblk157][cchunk16][mf8][q4][pxl16][j8]
constexpr size_t TPLANE    = 20578304;                   // 157*16*4096 shorts * 2B
constexpr size_t OFF_TPH   = 0;
constexpr size_t OFF_TPL   = OFF_TPH + TPLANE;           // 20,578,304
constexpr size_t OFF_BOXES = 41156608;                   // 8*22500*4 f32
constexpr size_t OFF_MS    = OFF_BOXES + 2880000;        // (unused now)
constexpr size_t OFF_KEYS  = OFF_MS + 720000;            // 8*22500 u64
constexpr size_t OFF_TBOX  = OFF_KEYS + 1440000;         // 8*2000*4 f32
constexpr size_t OFF_TS    = OFF_TBOX + 256000;          // 8*2000 f32
constexpr size_t OFF_SUP   = OFF_TS + 64000;             // 8*2000*32 u64
constexpr size_t OFF_KEEP  = OFF_SUP + 4096000;          // 8*64 u32
// feature planes: [b8][cic64][rr52][lk2][cc52][ci8] bf16 (rr/cc include zero halo)
constexpr size_t PPLANE    = 44318720;
constexpr size_t OFF_PH    = 50614656;
constexpr size_t OFF_PL    = OFF_PH + PPLANE;
// weight planes: [cot16][cic64][tap9][lk2][co32][ci8] bf16
constexpr size_t WPLANE    = 9437184;
constexpr size_t OFF_WH    = OFF_PL + PPLANE;
constexpr size_t OFF_WL    = OFF_WH + WPLANE;
// end ~158.1 MB

__device__ __forceinline__ void split2bf16(float v, unsigned short &hi, unsigned short &lo) {
    unsigned int u = __float_as_uint(v);
    unsigned int r = u + 0x7FFFu + ((u >> 16) & 1u);
    hi = (unsigned short)(r >> 16);
    float hf = __uint_as_float(((unsigned int)hi) << 16);
    float lf = v - hf;
    unsigned int u2 = __float_as_uint(lf);
    unsigned int r2 = u2 + 0x7FFFu + ((u2 >> 16) & 1u);
    lo = (unsigned short)(r2 >> 16);
}

__device__ __forceinline__ void gl_lds(const unsigned short* g, unsigned short* l) {
    __builtin_amdgcn_global_load_lds(
        (const __attribute__((address_space(1))) unsigned int*)(const void*)g,
        (__attribute__((address_space(3))) unsigned int*)(void*)l,
        16, 0, 0);
}

// ---------------- preprocess: feature -> hi/lo bf16 planes [b][cic][rr][lk][cc][8] ----------------
__global__ __launch_bounds__(256) void prep_feat(const float* __restrict__ f,
                                                 unsigned short* __restrict__ Ph,
                                                 unsigned short* __restrict__ Pl) {
    int id = blockIdx.x * 256 + threadIdx.x;
    int cc = id % 52; int r = id / 52;
    int rr = r % 52;  r /= 52;
    int cic = r % 64; int b = r / 64;
    int h = rr - 1, w = cc - 1;
    bool inb = (h >= 0 && h < HDIM && w >= 0 && w < WDIM);
    ushort8v hv0, lv0, hv1, lv1;
#pragma unroll
    for (int j = 0; j < 16; ++j) {
        float v = 0.f;
        if (inb) v = f[(((size_t)b * CIN + cic * 16 + j) * HDIM + h) * WDIM + w];
        unsigned short hi, lo;
        split2bf16(v, hi, lo);
        if (j < 8) { hv0[j] = hi; lv0[j] = lo; }
        else       { hv1[j - 8] = hi; lv1[j - 8] = lo; }
    }
    size_t rowb = (size_t)((b * 64 + cic) * 52 + rr) * 832;
    *(ushort8v*)&Ph[rowb + cc * 8]       = hv0;   // lk=0
    *(ushort8v*)&Ph[rowb + 416 + cc * 8] = hv1;   // lk=1
    *(ushort8v*)&Pl[rowb + cc * 8]       = lv0;
    *(ushort8v*)&Pl[rowb + 416 + cc * 8] = lv1;
}

// ---------------- preprocess: W1 -> hi/lo planes [cot16][cic][tap][lk][co32][8] ----------------
__global__ __launch_bounds__(256) void prep_w(const float* __restrict__ W1,
                                              unsigned short* __restrict__ Wh,
                                              unsigned short* __restrict__ Wl) {
    int id = blockIdx.x * 256 + threadIdx.x;
    int co = id % 32; int r = id / 32;
    int cic = r % 64; int cot = r / 64;
    int cog = cot * 32 + co;
    const float* src = W1 + ((size_t)cog * CIN + cic * 16) * 9;
    float v[144];
#pragma unroll
    for (int i = 0; i < 36; ++i) {
        float4 x = ((const float4*)src)[i];
        v[i * 4 + 0] = x.x; v[i * 4 + 1] = x.y; v[i * 4 + 2] = x.z; v[i * 4 + 3] = x.w;
    }
#pragma unroll
    for (int tap = 0; tap < 9; ++tap) {
        ushort8v hv0, lv0, hv1, lv1;
#pragma unroll
        for (int j = 0; j < 16; ++j) {
            unsigned short hi, lo;
            split2bf16(v[j * 9 + tap], hi, lo);
            if (j < 8) { hv0[j] = hi; lv0[j] = lo; }
            else       { hv1[j - 8] = hi; lv1[j - 8] = lo; }
        }
        size_t base = ((((size_t)(cot * 64 + cic)) * 9 + tap) * 2) * 256;
        *(ushort8v*)&Wh[base + co * 8]       = hv0;   // lk=0
        *(ushort8v*)&Wh[base + 256 + co * 8] = hv1;   // lk=1
        *(ushort8v*)&Wl[base + co * 8]       = lv0;
        *(ushort8v*)&Wl[base + 256 + co * 8] = lv1;
    }
}

// ---------------- conv 3x3 via split-bf16 MFMA 32x32x16, 4 blocks/CU (R6 616us version) ----------------
__global__ __launch_bounds__(256, 4) void conv_mfma(const unsigned short* __restrict__ FPh,
                                                    const unsigned short* __restrict__ FPl,
                                                    const unsigned short* __restrict__ WPh,
                                                    const unsigned short* __restrict__ WPl,
                                                    const float* __restrict__ b1,
                                                    unsigned short* __restrict__ Tph,
                                                    unsigned short* __restrict__ Tpl) {
    __shared__ unsigned short sAh[5120], sAl[5120];   // [row6][lk2][cc52][8] + slack
    __shared__ unsigned short sBh[4608], sBl[4608];   // [tap9][lk2][co32][8]

    int blk = blockIdx.x;
    int cot = blk & 15;
    int mt  = (blk >> 4) % 13;
    int b   = blk / 208;
    int co0 = cot * 32;
    int r0  = mt * 4;

    int t = threadIdx.x, wv = t >> 6, ln = t & 63;
    int lm = ln & 31, lk = ln >> 5;

    f32x16 acc[2];
#pragma unroll
    for (int jm = 0; jm < 2; ++jm)
#pragma unroll
        for (int rg = 0; rg < 16; ++rg) acc[jm][rg] = 0.f;

#pragma unroll 1
    for (int cic = 0; cic < 64; ++cic) {
        __syncthreads();
        const unsigned short* wH = WPh + (size_t)(cot * 64 + cic) * 4608;
        const unsigned short* wL = WPl + (size_t)(cot * 64 + cic) * 4608;
        const unsigned short* aH = FPh + (size_t)((b * 64 + cic) * 52 + r0) * 832;
        const unsigned short* aL = FPl + (size_t)((b * 64 + cic) * 52 + r0) * 832;
        if (wv == 0) {
#pragma unroll
            for (int s = 0; s < 9; ++s) gl_lds(wH + s * 512 + ln * 8, &sBh[s * 512]);
        } else if (wv == 1) {
#pragma unroll
            for (int s = 0; s < 9; ++s) gl_lds(wL + s * 512 + ln * 8, &sBl[s * 512]);
        } else if (wv == 2) {
#pragma unroll
            for (int s = 0; s < 10; ++s) gl_lds(aH + s * 512 + ln * 8, &sAh[s * 512]);
        } else {
#pragma unroll
            for (int s = 0; s < 10; ++s) gl_lds(aL + s * 512 + ln * 8, &sAl[s * 512]);
        }
        __syncthreads();

#pragma unroll
        for (int tap = 0; tap < 9; ++tap) {
            const int kh = tap / 3, kw = tap % 3;
            int arow = wv + kh;
            bf16x8 a[2][2], bh, bl;
#pragma unroll
            for (int jm = 0; jm < 2; ++jm) {
                int cc = jm * 32 + lm + kw;
                if (cc > 51) cc = 51;
                int ad = ((arow * 2 + lk) * 52 + cc) * 8;
                a[jm][0] = *(const bf16x8*)&sAh[ad];
                a[jm][1] = *(const bf16x8*)&sAl[ad];
            }
            {
                int bd = ((tap * 2 + lk) * 32 + lm) * 8;
                bh = *(const bf16x8*)&sBh[bd];
                bl = *(const bf16x8*)&sBl[bd];
            }
#pragma unroll
            for (int jm = 0; jm < 2; ++jm) {
                acc[jm] = __builtin_amdgcn_mfma_f32_32x32x16_bf16(a[jm][0], bh, acc[jm], 0, 0, 0);
                acc[jm] = __builtin_amdgcn_mfma_f32_32x32x16_bf16(a[jm][0], bl, acc[jm], 0, 0, 0);
                acc[jm] = __builtin_amdgcn_mfma_f32_32x32x16_bf16(a[jm][1], bh, acc[jm], 0, 0, 0);
            }
        }
    }

    int h = r0 + wv;
    if (h >= HDIM) return;
    int co = co0 + lm;
    float bv = b1[co];
#pragma unroll
    for (int jm = 0; jm < 2; ++jm) {
#pragma unroll
        for (int rg = 0; rg < 16; ++rg) {
            int w = jm * 32 + (rg & 3) + 8 * (rg >> 2) + 4 * lk;
            if (w < WDIM) {
                float v = fmaxf(acc[jm][rg] + bv, 0.f);
                unsigned short hi, lo;
                split2bf16(v, hi, lo);
                int px = b * 2500 + h * 50 + w;
                size_t sa = (((((size_t)(px >> 7) * 16 + (co >> 5)) * 8 + ((px >> 4) & 7)) * 4
                              + ((co >> 3) & 3)) * 16 + (px & 15)) * 8 + (co & 7);
                Tph[sa] = hi;
                Tpl[sa] = lo;
            }
        }
    }
}

// ---------------- projection (MFMA) + decode + key build ----------------
__global__ __launch_bounds__(256) void proj_decode_mfma(const unsigned short* __restrict__ Tph,
                                                        const unsigned short* __restrict__ Tpl,
                                                        const float* __restrict__ W2,
                                                        const float* __restrict__ b2,
                                                        const float* __restrict__ W3,
                                                        const float* __restrict__ b3,
                                                        float* __restrict__ boxes,
                                                        unsigned long long* __restrict__ keys) {
    __shared__ unsigned short sTh[4096], sTl[4096];
    __shared__ unsigned short sWh[1536], sWl[1536];
    __shared__ float pout[128 * 46];

    int blk = blockIdx.x;
    int px0 = blk * 128;
    int t = threadIdx.x, wv = t >> 6, ln = t & 63;
    int lm = ln & 15, q = ln >> 4;

    f32x4 acc[2][3];
#pragma unroll
    for (int jm = 0; jm < 2; ++jm)
#pragma unroll
        for (int nf = 0; nf < 3; ++nf) acc[jm][nf] = (f32x4){0.f, 0.f, 0.f, 0.f};

#pragma unroll 1
    for (int cc16 = 0; cc16 < 16; ++cc16) {
        __syncthreads();
        size_t base = ((size_t)blk * 16 + cc16) * 4096;
        if (wv == 0) {
#pragma unroll
            for (int s = 0; s < 4; ++s) gl_lds(Tph + base + s * 512 + ln * 8, &sTh[s * 512]);
        } else if (wv == 1) {
#pragma unroll
            for (int s = 4; s < 8; ++s) gl_lds(Tph + base + s * 512 + ln * 8, &sTh[s * 512]);
        } else if (wv == 2) {
#pragma unroll
            for (int s = 0; s < 4; ++s) gl_lds(Tpl + base + s * 512 + ln * 8, &sTl[s * 512]);
        } else {
#pragma unroll
            for (int s = 4; s < 8; ++s) gl_lds(Tpl + base + s * 512 + ln * 8, &sTl[s * 512]);
        }
        int c0 = cc16 * 32;
        for (int idx = t; idx < 1536; idx += 256) {
            int o = idx >> 5, ci = idx & 31;
            float v = 0.f;
            if (o < 36) v = W2[o * 512 + c0 + ci];
            else if (o < 45) v = W3[(o - 36) * 512 + c0 + ci];
            unsigned short hi, lo;
            split2bf16(v, hi, lo);
            int ad = (((o >> 4) * 4 + (ci >> 3)) * 16 + (o & 15)) * 8 + (ci & 7);
            sWh[ad] = hi; sWl[ad] = lo;
        }
        __syncthreads();

        bf16x8 a[2][2], bb[3][2];
#pragma unroll
        for (int jm = 0; jm < 2; ++jm) {
            int mf = wv * 2 + jm;
            int ad = ((mf * 4 + q) * 16 + lm) * 8;
            a[jm][0] = *(const bf16x8*)&sTh[ad];
            a[jm][1] = *(const bf16x8*)&sTl[ad];
        }
#pragma unroll
        for (int nf = 0; nf < 3; ++nf) {
            int ad = ((nf * 4 + q) * 16 + lm) * 8;
            bb[nf][0] = *(const bf16x8*)&sWh[ad];
            bb[nf][1] = *(const bf16x8*)&sWl[ad];
        }
#pragma unroll
        for (int jm = 0; jm < 2; ++jm)
#pragma unroll
            for (int nf = 0; nf < 3; ++nf) {
                acc[jm][nf] = __builtin_amdgcn_mfma_f32_16x16x32_bf16(a[jm][0], bb[nf][0], acc[jm][nf], 0, 0, 0);
                acc[jm][nf] = __builtin_amdgcn_mfma_f32_16x16x32_bf16(a[jm][0], bb[nf][1], acc[jm][nf], 0, 0, 0);
                acc[jm][nf] = __builtin_amdgcn_mfma_f32_16x16x32_bf16(a[jm][1], bb[nf][0], acc[jm][nf], 0, 0, 0);
            }
    }
    __syncthreads();
#pragma unroll
    for (int jm = 0; jm < 2; ++jm)
#pragma unroll
        for (int nf = 0; nf < 3; ++nf) {
            int o = nf * 16 + lm;
            if (o < 45) {
                float bias = (o < 36) ? b2[o] : b3[o - 36];
#pragma unroll
                for (int rg = 0; rg < 4; ++rg) {
                    int pxl = (wv * 2 + jm) * 16 + q * 4 + rg;
                    pout[pxl * 46 + o] = acc[jm][nf][rg] + bias;
                }
            }
        }
    __syncthreads();

    const float AW[9] = {90.50966799187809f, 128.0f, 181.01933598375618f,
                         181.01933598375618f, 256.0f, 362.03867196751236f,
                         362.03867196751236f, 512.0f, 724.0773439350247f};
    const float AH[9] = {181.01933598375618f, 128.0f, 90.50966799187809f,
                         362.03867196751236f, 256.0f, 181.01933598375618f,
                         724.0773439350247f, 512.0f, 362.03867196751236f};
    const float CLIPV = 4.135166556742356f;
    const float IMG = 1600.0f;

    for (int it = t; it < 128 * 9; it += 256) {
        int pxl = it / 9, a = it - pxl * 9;
        int pxg = px0 + pxl;
        if (pxg >= 20000) continue;
        int b = pxg / 2500, rem = pxg % 2500;
        int h = rem / 50, w = rem % 50;

        float tx = pout[pxl * 46 + a * 4 + 0];
        float ty = pout[pxl * 46 + a * 4 + 1];
        float tw = pout[pxl * 46 + a * 4 + 2];
        float th = pout[pxl * 46 + a * 4 + 3];
        float lg = pout[pxl * 46 + 36 + a];

        float s = 1.0f / (1.0f + expf(-lg));

        float cx = ((float)w + 0.5f) * 32.0f;
        float cy = ((float)h + 0.5f) * 32.0f;
        float x1a = cx - 0.5f * AW[a];
        float x2a = cx + 0.5f * AW[a];
        float y1a = cy - 0.5f * AH[a];
        float y2a = cy + 0.5f * AH[a];
        float waf = x2a - x1a;
        float haf = y2a - y1a;
        float cxa = x1a + 0.5f * waf;
        float cya = y1a + 0.5f * haf;

        float twc = tw < CLIPV ? tw : CLIPV;
        float thc = th < CLIPV ? th : CLIPV;
        float pxc = tx * waf + cxa;
        float pyc = ty * haf + cya;
        float pw  = expf(twc) * waf;
        float ph  = expf(thc) * haf;

        float x1 = pxc - 0.5f * pw;
        float y1 = pyc - 0.5f * ph;
        float x2 = pxc + 0.5f * pw;
        float y2 = pyc + 0.5f * ph;
        x1 = fminf(fmaxf(x1, 0.f), IMG);
        y1 = fminf(fmaxf(y1, 0.f), IMG);
        x2 = fminf(fmaxf(x2, 0.f), IMG);
        y2 = fminf(fmaxf(y2, 0.f), IMG);

        float bw = x2 - x1, bh = y2 - y1;
        bool valid = (s >= 0.1f) && (bw > 16.0f) && (bh > 16.0f);
        float m = valid ? s : -1.0f;

        int idx = (h * WDIM + w) * NA + a;
        size_t gi = (size_t)b * NANCH + idx;
        ((float4*)boxes)[gi] = make_float4(x1, y1, x2, y2);
        unsigned int u = __float_as_uint(m);
        unsigned int k32 = (u & 0x80000000u) ? ~u : (u | 0x80000000u);
        keys[gi] = ((unsigned long long)k32 << 15) | (unsigned long long)(32767 - idx);
    }
}

// ---------------- exact stable top-2000: 6x8-bit radix select w/ per-wave hists + bitonic ----------------
__global__ __launch_bounds__(1024) void select_sort_kernel(const unsigned long long* __restrict__ keys,
                                                           const float* __restrict__ boxes,
                                                           float* __restrict__ top_boxes,
                                                           float* __restrict__ top_s) {
    int b = blockIdx.x;
    int t = threadIdx.x;
    int wv = t >> 6;
    const unsigned long long* kb = keys + (size_t)b * NANCH;

    __shared__ unsigned int whist[16][256];   // per-wave histograms (16 KB)
    __shared__ unsigned int hist[256];
    __shared__ int s_chosen, s_rnew;
    __shared__ unsigned int s_cnt;
    __shared__ unsigned long long skeys[2048];

    const int widths[6] = {8, 8, 8, 8, 8, 7};
    unsigned long long prefix = 0;
    int bitsdone = 0;
    int r = PRE_N;

    for (int p = 0; p < 6; ++p) {
        int width = widths[p];
        int bins = 1 << width;
        int shift = 47 - bitsdone - width;
        for (int i = t; i < 16 * 256; i += 1024) ((unsigned int*)whist)[i] = 0;
        __syncthreads();
        for (int i = t; i < NANCH; i += 1024) {
            unsigned long long k = kb[i];
            if ((k >> (47 - bitsdone)) == prefix)
                atomicAdd(&whist[wv][(unsigned)((k >> shift) & (unsigned long long)(bins - 1))], 1u);
        }
        __syncthreads();
        if (t < bins) {
            unsigned int s = 0;
#pragma unroll
            for (int w = 0; w < 16; ++w) s += whist[w][t];
            hist[t] = s;
        }
        __syncthreads();
        if (t == 0) {
            int acc = 0, chosen = 0, rnew = 1;
            for (int d = bins - 1; d >= 0; --d) {
                int hv = (int)hist[d];
                if (acc + hv >= r) { chosen = d; rnew = r - acc; break; }
                acc += hv;
            }
            s_chosen = chosen;
            s_rnew = rnew;
        }
        __syncthreads();
        prefix = (prefix << width) | (unsigned long long)s_chosen;
        bitsdone += width;
        r = s_rnew;
        __syncthreads();
    }
    unsigned long long Kst = prefix;   // exact rank-2000 key (47-bit)

    if (t == 0) s_cnt = 0;
    __syncthreads();
    for (int i = t; i < NANCH; i += 1024) {
        unsigned long long k = kb[i];
        if (k >= Kst) {
            unsigned int p = atomicAdd(&s_cnt, 1u);
            if (p < 2048) skeys[p] = k;
        }
    }
    __syncthreads();
    unsigned int cnt = s_cnt;
    for (int i = t; i < 2048; i += 1024)
        if (i >= (int)cnt) skeys[i] = 0ull;
    for (int k = 2; k <= 2048; k <<= 1) {
        for (int j = k >> 1; j > 0; j >>= 1) {
            __syncthreads();
            for (int i = t; i < 2048; i += 1024) {
                int l = i ^ j;
                if (l > i) {
                    unsigned long long a = skeys[i], c = skeys[l];
                    bool up = ((i & k) == 0);
                    if (up ? (a < c) : (a > c)) { skeys[i] = c; skeys[l] = a; }
                }
            }
        }
    }
    __syncthreads();
    for (int i = t; i < PRE_N; i += 1024) {
        unsigned long long k = skeys[i];
        unsigned int k32 = (unsigned int)(k >> 15);
        float m = (k32 & 0x80000000u) ? __uint_as_float(k32 & 0x7FFFFFFFu)
                                      : __uint_as_float(~k32);
        unsigned int idx = 32767u - (unsigned int)(k & 32767ull);
        size_t gi = (size_t)b * NANCH + idx;
        top_s[b * PRE_N + i] = m;
        ((float4*)top_boxes)[b * PRE_N + i] = ((const float4*)boxes)[gi];
    }
}

// ---------------- IoU suppression bit-matrix ----------------
__global__ __launch_bounds__(256) void sup_kernel(const float* __restrict__ top_boxes,
                                                  unsigned long long* __restrict__ supm) {
    int blk = blockIdx.x;
    int b = blk / 125;
    int chunk = blk % 125;
    int t = threadIdx.x;

    __shared__ float bx1[PRE_N], by1[PRE_N], bx2[PRE_N], by2[PRE_N];
    for (int i = t; i < PRE_N; i += 256) {
        float4 v = ((const float4*)top_boxes)[b * PRE_N + i];
        bx1[i] = v.x; by1[i] = v.y; bx2[i] = v.z; by2[i] = v.w;
    }
    __syncthreads();

    int wave = t >> 6, lane = t & 63;
    for (int rr = 0; rr < 4; ++rr) {
        int i = chunk * 16 + wave * 4 + rr;
        float ax1 = bx1[i], ay1 = by1[i], ax2 = bx2[i], ay2 = by2[i];
        float aarea = (ax2 - ax1) * (ay2 - ay1);
        for (int jw = 0; jw < 32; ++jw) {
            int j = jw * 64 + lane;
            bool sup = false;
            if (j > i && j < PRE_N) {
                float jx1 = bx1[j], jy1 = by1[j], jx2 = bx2[j], jy2 = by2[j];
                float ix1 = fmaxf(ax1, jx1), iy1 = fmaxf(ay1, jy1);
                float ix2 = fminf(ax2, jx2), iy2 = fminf(ay2, jy2);
                float iw = fmaxf(ix2 - ix1, 0.f);
                float ih = fmaxf(iy2 - iy1, 0.f);
                float inter = iw * ih;
                float barea = (jx2 - jx1) * (jy2 - jy1);
                float iou = inter / (aarea + barea - inter + 1e-9f);
                sup = iou > 0.7f;
            }
            unsigned long long m = __ballot(sup);
            if (lane == 0) supm[((size_t)b * PRE_N + i) * 32 + jw] = m;
        }
    }
}

// ---------------- fused: tiled NMS scan (wave 0) + stable top-100 finalize ----------------
__global__ __launch_bounds__(256) void nms_fin_kernel(const float* __restrict__ top_s,
                                                      const unsigned long long* __restrict__ supm,
                                                      const float* __restrict__ top_boxes,
                                                      float* __restrict__ out) {
    int b = blockIdx.x;
    int t = threadIdx.x;
    __shared__ unsigned int kw[64];
    __shared__ int wpre[65];

    if (t < 64) {
        int lane = t;
        unsigned int alive = 0;
        for (int q = 0; q < 32; ++q) {
            int i = lane * 32 + q;
            if (i < PRE_N && top_s[b * PRE_N + i] > 0.f) alive |= (1u << q);
        }
        const unsigned long long* sm = supm + (size_t)b * PRE_N * 32;
        const unsigned int* sup32 = (const unsigned int*)sm;

        for (int tt = 0; tt < 32; ++tt) {
            unsigned int alo = __shfl(alive, 2 * tt);
            unsigned int ahi = __shfl(alive, 2 * tt + 1);
            unsigned long long talive = (unsigned long long)alo | ((unsigned long long)ahi << 32);
            int i_row = tt * 64 + lane;
            unsigned long long rm = (i_row < PRE_N) ? sm[(size_t)i_row * 32 + tt] : 0ull;

            unsigned long long kept = 0, rem = talive;
            while (rem) {
                int j = __builtin_ctzll(rem);
                kept |= (1ull << j);
                unsigned long long rmj = __shfl(rm, j);
                rem &= ~rmj;
                rem &= ~(1ull << j);
            }

            unsigned int oracc = 0;
            unsigned long long kk = kept;
            while (kk) {
                int j0 = __builtin_ctzll(kk); kk &= kk - 1;
                int j1 = -1, j2 = -1, j3 = -1;
                if (kk) { j1 = __builtin_ctzll(kk); kk &= kk - 1; }
                if (kk) { j2 = __builtin_ctzll(kk); kk &= kk - 1; }
                if (kk) { j3 = __builtin_ctzll(kk); kk &= kk - 1; }
                unsigned int v0 = sup32[(size_t)(tt * 64 + j0) * 64 + lane];
                unsigned int v1 = (j1 >= 0) ? sup32[(size_t)(tt * 64 + j1) * 64 + lane] : 0u;
                unsigned int v2 = (j2 >= 0) ? sup32[(size_t)(tt * 64 + j2) * 64 + lane] : 0u;
                unsigned int v3 = (j3 >= 0) ? sup32[(size_t)(tt * 64 + j3) * 64 + lane] : 0u;
                oracc |= v0 | v1 | v2 | v3;
            }
            alive &= ~oracc;
            if (lane == 2 * tt)     alive = (unsigned int)kept;
            if (lane == 2 * tt + 1) alive = (unsigned int)(kept >> 32);
        }
        kw[lane] = alive;
    }
    __syncthreads();
    if (t == 0) {
        int run = 0;
        for (int w = 0; w < 64; ++w) { wpre[w] = run; run += __popc(kw[w]); }
        wpre[64] = run;
    }
    __syncthreads();
    int total = wpre[64];
    float* out_boxes  = out;
    float* out_scores = out + NB * POST_N * 4;
    for (int i = t; i < PRE_N; i += 256) {
        unsigned int w = kw[i >> 5];
        bool kept = (w >> (i & 31)) & 1u;
        int rk = wpre[i >> 5] + __popc(w & ((1u << (i & 31)) - 1u));
        int pos = kept ? rk : total + (i - rk);
        if (pos < POST_N) {
            out_scores[b * POST_N + pos] = kept ? top_s[b * PRE_N + i] : -1.0f;
            ((float4*)out_boxes)[b * POST_N + pos] = ((const float4*)top_boxes)[b * PRE_N + i];
        }
    }
}

// ---------------- launch ----------------
extern "C" void kernel_launch(void* const* d_in, const int* in_sizes, int n_in,
                              void* d_out, int out_size, void* d_ws, size_t ws_size,
                              hipStream_t stream) {
    const float* features = (const float*)d_in[0];
    const float* W1 = (const float*)d_in[1];
    const float* b1 = (const float*)d_in[2];
    const float* W2 = (const float*)d_in[3];
    const float* b2 = (const float*)d_in[4];
    const float* W3 = (const float*)d_in[5];
    const float* b3 = (const float*)d_in[6];
    float* out = (float*)d_out;
    char* ws = (char*)d_ws;

    unsigned short* Tph = (unsigned short*)(ws + OFF_TPH);
    unsigned short* Tpl = (unsigned short*)(ws + OFF_TPL);
    float* boxes   = (float*)(ws + OFF_BOXES);
    unsigned long long* keys = (unsigned long long*)(ws + OFF_KEYS);
    float* top_boxes = (float*)(ws + OFF_TBOX);
    float* top_s     = (float*)(ws + OFF_TS);
    unsigned long long* supm = (unsigned long long*)(ws + OFF_SUP);
    unsigned short* FPh = (unsigned short*)(ws + OFF_PH);
    unsigned short* FPl = (unsigned short*)(ws + OFF_PL);
    unsigned short* WPh = (unsigned short*)(ws + OFF_WH);
    unsigned short* WPl = (unsigned short*)(ws + OFF_WL);

    prep_feat<<<5408, 256, 0, stream>>>(features, FPh, FPl);
    prep_w<<<128, 256, 0, stream>>>(W1, WPh, WPl);
    conv_mfma<<<1664, 256, 0, stream>>>(FPh, FPl, WPh, WPl, b1, Tph, Tpl);
    proj_decode_mfma<<<157, 256, 0, stream>>>(Tph, Tpl, W2, b2, W3, b3, boxes, keys);
    select_sort_kernel<<<NB, 1024, 0, stream>>>(keys, boxes, top_boxes, top_s);
    sup_kernel<<<NB * 125, 256, 0, stream>>>(top_boxes, supm);
    nms_fin_kernel<<<NB, 256, 0, stream>>>(top_s, supm, top_boxes, out);
}

// Round 9
// 1117.176 us; speedup vs baseline: 1.1848x; 1.0312x over previous
//
#include <hip/hip_runtime.h>
#include <cstdint>

#define NB 8
#define CIN 1024
#define HDIM 50
#define WDIM 50
#define COUT 512
#define NA 9
#define NANCH (HDIM*WDIM*NA)   /* 22500 */
#define PRE_N 2000
#define POST_N 100

typedef __attribute__((ext_vector_type(8))) short bf16x8;
typedef __attribute__((ext_vector_type(4))) float f32x4;
typedef __attribute__((ext_vector_type(16))) float f32x16;
typedef __attribute__((ext_vector_type(8))) unsigned short ushort8v;

// ---------------- workspace layout (bytes) ----------------
// t planes (bf16 hi/lo) in proj-A-frag order: [pxblk157][cchunk16][mf8][q4][pxl16][j8]
constexpr size_t TPLANE    = 20578304;                   // 157*16*4096 shorts * 2B
constexpr size_t OFF_TPH   = 0;
constexpr size_t OFF_TPL   = 20578304;
constexpr size_t OFF_BOXES = 41156608;                   // 8*22500*4 f32
constexpr size_t OFF_KEYS  = 44036608;                   // 8*22500 u64
constexpr size_t OFF_TBOX  = 45476608;                   // 8*2000*4 f32
constexpr size_t OFF_TS    = 45732608;                   // 8*2000 f32
constexpr size_t OFF_SUP   = 45796608;                   // 8*2000*32 u64
// feature planes, flat-padded-pixel layout: [b8][cic64][lk2][q2976][ci8] bf16
//   q = p' + 53, p' = rr*52+cc on the 52x52 zero-padded grid (rr,cc in 0..51)
constexpr size_t QDIM      = 2976;                       // covers q up to 2975 (stage max 2975)
constexpr size_t PLSTRIDE  = QDIM * 8;                   // shorts per (b,cic,lk) = 23808
constexpr size_t PPLANE    = 48758784;                   // 8*64*2*23808*2B
constexpr size_t OFF_PH    = 49892864;
constexpr size_t OFF_PL    = OFF_PH + PPLANE;            // 98,651,648
// weight planes: [cot8][cic64][tap9][lk2][co64][ci8] bf16
constexpr size_t WPLANE    = 9437184;
constexpr size_t OFF_WH    = 147410432;
constexpr size_t OFF_WL    = OFF_WH + WPLANE;            // end ~166.3 MB

__device__ __forceinline__ void split2bf16(float v, unsigned short &hi, unsigned short &lo) {
    unsigned int u = __float_as_uint(v);
    unsigned int r = u + 0x7FFFu + ((u >> 16) & 1u);
    hi = (unsigned short)(r >> 16);
    float hf = __uint_as_float(((unsigned int)hi) << 16);
    float lf = v - hf;
    unsigned int u2 = __float_as_uint(lf);
    unsigned int r2 = u2 + 0x7FFFu + ((u2 >> 16) & 1u);
    lo = (unsigned short)(r2 >> 16);
}

__device__ __forceinline__ void gl_lds(const unsigned short* g, unsigned short* l) {
    __builtin_amdgcn_global_load_lds(
        (const __attribute__((address_space(1))) unsigned int*)(const void*)g,
        (__attribute__((address_space(3))) unsigned int*)(void*)l,
        16, 0, 0);
}

// ---------------- fused preprocess: features (blocks 0..5951) + weights (5952..6079) ----------------
__global__ __launch_bounds__(256) void prep_all(const float* __restrict__ f,
                                                const float* __restrict__ W1,
                                                unsigned short* __restrict__ Ph,
                                                unsigned short* __restrict__ Pl,
                                                unsigned short* __restrict__ Wh,
                                                unsigned short* __restrict__ Wl) {
    int blk = blockIdx.x;
    if (blk < 5952) {
        // features -> [b][cic][lk][q][8], zeros in halo/pad
        int id = blk * 256 + threadIdx.x;
        int q = id % (int)QDIM; int r = id / (int)QDIM;
        int cic = r % 64; int b = r / 64;
        int pp = q - 53;
        int rr = pp / 52, cc = pp - rr * 52;
        int h = rr - 1, w = cc - 1;
        bool inb = (pp >= 0) && (pp < 2704) && (h >= 0) && (h < HDIM) && (w >= 0) && (w < WDIM);
        ushort8v hv0, lv0, hv1, lv1;
#pragma unroll
        for (int j = 0; j < 16; ++j) {
            float v = 0.f;
            if (inb) v = f[(((size_t)b * CIN + cic * 16 + j) * HDIM + h) * WDIM + w];
            unsigned short hi, lo;
            split2bf16(v, hi, lo);
            if (j < 8) { hv0[j] = hi; lv0[j] = lo; }
            else       { hv1[j - 8] = hi; lv1[j - 8] = lo; }
        }
        size_t b0 = ((size_t)((b * 64 + cic) * 2 + 0)) * PLSTRIDE + (size_t)q * 8;
        size_t b1 = ((size_t)((b * 64 + cic) * 2 + 1)) * PLSTRIDE + (size_t)q * 8;
        *(ushort8v*)&Ph[b0] = hv0;
        *(ushort8v*)&Ph[b1] = hv1;
        *(ushort8v*)&Pl[b0] = lv0;
        *(ushort8v*)&Pl[b1] = lv1;
    } else {
        // weights -> [cot8][cic][tap][lk][co64][8]
        int id = (blk - 5952) * 256 + threadIdx.x;
        int co = id % 64; int r = id / 64;
        int cic = r % 64; int cot = r / 64;
        int cog = cot * 64 + co;
        const float* src = W1 + ((size_t)cog * CIN + cic * 16) * 9;
        float v[144];
#pragma unroll
        for (int i = 0; i < 36; ++i) {
            float4 x = ((const float4*)src)[i];
            v[i * 4 + 0] = x.x; v[i * 4 + 1] = x.y; v[i * 4 + 2] = x.z; v[i * 4 + 3] = x.w;
        }
#pragma unroll
        for (int tap = 0; tap < 9; ++tap) {
            ushort8v hv0, lv0, hv1, lv1;
#pragma unroll
            for (int j = 0; j < 16; ++j) {
                unsigned short hi, lo;
                split2bf16(v[j * 9 + tap], hi, lo);
                if (j < 8) { hv0[j] = hi; lv0[j] = lo; }
                else       { hv1[j - 8] = hi; lv1[j - 8] = lo; }
            }
            size_t base = (((size_t)(cot * 64 + cic) * 9 + tap) * 2) * 512;
            *(ushort8v*)&Wh[base + co * 8]       = hv0;   // lk=0
            *(ushort8v*)&Wh[base + 512 + co * 8] = hv1;   // lk=1
            *(ushort8v*)&Wl[base + co * 8]       = lv0;
            *(ushort8v*)&Wl[base + 512 + co * 8] = lv1;
        }
    }
}

// ---------------- conv 3x3: flat-p' implicit GEMM, split-bf16 MFMA 32x32x16 ----------------
// grid: 704 = b(8) x ptile(11) x cot(8). Block: 256 consecutive padded-pixels (8 m-frags) x 64 co.
// Wave wv owns m-frags {2wv, 2wv+1}; tap (kh,kw) = flat offset (kh-1)*52+(kw-1).
__global__ __launch_bounds__(256, 2) void conv_mfma(const unsigned short* __restrict__ FPh,
                                                    const unsigned short* __restrict__ FPl,
                                                    const unsigned short* __restrict__ WPh,
                                                    const unsigned short* __restrict__ WPl,
                                                    const float* __restrict__ b1,
                                                    unsigned short* __restrict__ Tph,
                                                    unsigned short* __restrict__ Tpl) {
    __shared__ unsigned short sA[2][2][3072];   // [hl][lk][384 entries x 8] = 24,576 B
    __shared__ unsigned short sB[2][9216];      // [hl][tap9][lk2][co64][8]  = 36,864 B

    int blk = blockIdx.x;
    int cot = blk & 7;
    int ptile = (blk >> 3) % 11;
    int b = blk / 88;
    int co0 = cot * 64;
    int P0 = 32 + ptile * 256;      // base p' of this tile; staged q range = [P0, P0+383]

    int t = threadIdx.x, wv = t >> 6, ln = t & 63;
    int lm = ln & 31, lk = ln >> 5;

    f32x16 acc[2][2];
#pragma unroll
    for (int jm = 0; jm < 2; ++jm)
#pragma unroll
        for (int jn = 0; jn < 2; ++jn)
#pragma unroll
            for (int rg = 0; rg < 16; ++rg) acc[jm][jn][rg] = 0.f;

#pragma unroll 1
    for (int cic = 0; cic < 64; ++cic) {
        __syncthreads();
        // 60 staging chunks: A = 24 (hl2 x lk2 x 6), B = 36 (hl2 x 18); wave wv does ids [wv*15, +15)
#pragma unroll
        for (int k = 0; k < 15; ++k) {
            int id = wv * 15 + k;
            if (id < 24) {
                int hl = id / 12, lkc = (id / 6) & 1, s = id % 6;
                const unsigned short* pl = hl ? FPl : FPh;
                const unsigned short* src = pl
                    + ((size_t)((b * 64 + cic) * 2 + lkc)) * PLSTRIDE
                    + (size_t)P0 * 8 + s * 512 + ln * 8;
                gl_lds(src, &sA[hl][lkc][s * 512]);
            } else {
                int j = id - 24;
                int hl = j / 18, s = j % 18;
                const unsigned short* pl = hl ? WPl : WPh;
                const unsigned short* src = pl + (size_t)(cot * 64 + cic) * 9216 + s * 512 + ln * 8;
                gl_lds(src, &sB[hl][s * 512]);
            }
        }
        __syncthreads();

#pragma unroll
        for (int tap = 0; tap < 9; ++tap) {
            const int kh = tap / 3, kw = tap % 3;
            const int dlt = (kh - 1) * 52 + (kw - 1);   // flat tap offset
            bf16x8 a[2][2], bb[2][2];
#pragma unroll
            for (int jm = 0; jm < 2; ++jm) {
                int e = (wv * 2 + jm) * 32 + lm + dlt + 53;   // LDS entry, 0..361
                int ad = e * 8;
                a[jm][0] = *(const bf16x8*)&sA[0][lk][ad];
                a[jm][1] = *(const bf16x8*)&sA[1][lk][ad];
            }
#pragma unroll
            for (int jn = 0; jn < 2; ++jn) {
                int bd = tap * 1024 + lk * 512 + (jn * 32 + lm) * 8;
                bb[jn][0] = *(const bf16x8*)&sB[0][bd];
                bb[jn][1] = *(const bf16x8*)&sB[1][bd];
            }
#pragma unroll
            for (int jm = 0; jm < 2; ++jm)
#pragma unroll
                for (int jn = 0; jn < 2; ++jn) {
                    acc[jm][jn] = __builtin_amdgcn_mfma_f32_32x32x16_bf16(a[jm][0], bb[jn][0], acc[jm][jn], 0, 0, 0);
                    acc[jm][jn] = __builtin_amdgcn_mfma_f32_32x32x16_bf16(a[jm][0], bb[jn][1], acc[jm][jn], 0, 0, 0);
                    acc[jm][jn] = __builtin_amdgcn_mfma_f32_32x32x16_bf16(a[jm][1], bb[jn][0], acc[jm][jn], 0, 0, 0);
                }
        }
    }

    // epilogue: bias+relu, split to bf16 hi/lo, store in proj-A-frag plane order
#pragma unroll
    for (int jn = 0; jn < 2; ++jn) {
        int co = co0 + jn * 32 + lm;
        float bv = b1[co];
#pragma unroll
        for (int jm = 0; jm < 2; ++jm) {
#pragma unroll
            for (int rg = 0; rg < 16; ++rg) {
                int mrow = (rg & 3) + 8 * (rg >> 2) + 4 * lk;
                int pp = P0 + (wv * 2 + jm) * 32 + mrow;
                int rr = pp / 52, cc = pp - rr * 52;
                int h = rr - 1, w = cc - 1;
                if ((unsigned)h < HDIM && (unsigned)w < WDIM) {
                    float v = fmaxf(acc[jm][jn][rg] + bv, 0.f);
                    unsigned short hi, lo;
                    split2bf16(v, hi, lo);
                    int px = b * 2500 + h * 50 + w;
                    size_t sa = (((((size_t)(px >> 7) * 16 + (co >> 5)) * 8 + ((px >> 4) & 7)) * 4
                                  + ((co >> 3) & 3)) * 16 + (px & 15)) * 8 + (co & 7);
                    Tph[sa] = hi;
                    Tpl[sa] = lo;
                }
            }
        }
    }
}

// ---------------- projection (MFMA) + decode + key build ----------------
__global__ __launch_bounds__(256) void proj_decode_mfma(const unsigned short* __restrict__ Tph,
                                                        const unsigned short* __restrict__ Tpl,
                                                        const float* __restrict__ W2,
                                                        const float* __restrict__ b2,
                                                        const float* __restrict__ W3,
                                                        const float* __restrict__ b3,
                                                        float* __restrict__ boxes,
                                                        unsigned long long* __restrict__ keys) {
    __shared__ unsigned short sTh[4096], sTl[4096];
    __shared__ unsigned short sWh[1536], sWl[1536];
    __shared__ float pout[128 * 46];

    int blk = blockIdx.x;
    int px0 = blk * 128;
    int t = threadIdx.x, wv = t >> 6, ln = t & 63;
    int lm = ln & 15, q = ln >> 4;

    f32x4 acc[2][3];
#pragma unroll
    for (int jm = 0; jm < 2; ++jm)
#pragma unroll
        for (int nf = 0; nf < 3; ++nf) acc[jm][nf] = (f32x4){0.f, 0.f, 0.f, 0.f};

#pragma unroll 1
    for (int cc16 = 0; cc16 < 16; ++cc16) {
        __syncthreads();
        size_t base = ((size_t)blk * 16 + cc16) * 4096;
        if (wv == 0) {
#pragma unroll
            for (int s = 0; s < 4; ++s) gl_lds(Tph + base + s * 512 + ln * 8, &sTh[s * 512]);
        } else if (wv == 1) {
#pragma unroll
            for (int s = 4; s < 8; ++s) gl_lds(Tph + base + s * 512 + ln * 8, &sTh[s * 512]);
        } else if (wv == 2) {
#pragma unroll
            for (int s = 0; s < 4; ++s) gl_lds(Tpl + base + s * 512 + ln * 8, &sTl[s * 512]);
        } else {
#pragma unroll
            for (int s = 4; s < 8; ++s) gl_lds(Tpl + base + s * 512 + ln * 8, &sTl[s * 512]);
        }
        int c0 = cc16 * 32;
        for (int idx = t; idx < 1536; idx += 256) {
            int o = idx >> 5, ci = idx & 31;
            float v = 0.f;
            if (o < 36) v = W2[o * 512 + c0 + ci];
            else if (o < 45) v = W3[(o - 36) * 512 + c0 + ci];
            unsigned short hi, lo;
            split2bf16(v, hi, lo);
            int ad = (((o >> 4) * 4 + (ci >> 3)) * 16 + (o & 15)) * 8 + (ci & 7);
            sWh[ad] = hi; sWl[ad] = lo;
        }
        __syncthreads();

        bf16x8 a[2][2], bb[3][2];
#pragma unroll
        for (int jm = 0; jm < 2; ++jm) {
            int mf = wv * 2 + jm;
            int ad = ((mf * 4 + q) * 16 + lm) * 8;
            a[jm][0] = *(const bf16x8*)&sTh[ad];
            a[jm][1] = *(const bf16x8*)&sTl[ad];
        }
#pragma unroll
        for (int nf = 0; nf < 3; ++nf) {
            int ad = ((nf * 4 + q) * 16 + lm) * 8;
            bb[nf][0] = *(const bf16x8*)&sWh[ad];
            bb[nf][1] = *(const bf16x8*)&sWl[ad];
        }
#pragma unroll
        for (int jm = 0; jm < 2; ++jm)
#pragma unroll
            for (int nf = 0; nf < 3; ++nf) {
                acc[jm][nf] = __builtin_amdgcn_mfma_f32_16x16x32_bf16(a[jm][0], bb[nf][0], acc[jm][nf], 0, 0, 0);
                acc[jm][nf] = __builtin_amdgcn_mfma_f32_16x16x32_bf16(a[jm][0], bb[nf][1], acc[jm][nf], 0, 0, 0);
                acc[jm][nf] = __builtin_amdgcn_mfma_f32_16x16x32_bf16(a[jm][1], bb[nf][0], acc[jm][nf], 0, 0, 0);
            }
    }
    __syncthreads();
#pragma unroll
    for (int jm = 0; jm < 2; ++jm)
#pragma unroll
        for (int nf = 0; nf < 3; ++nf) {
            int o = nf * 16 + lm;
            if (o < 45) {
                float bias = (o < 36) ? b2[o] : b3[o - 36];
#pragma unroll
                for (int rg = 0; rg < 4; ++rg) {
                    int pxl = (wv * 2 + jm) * 16 + q * 4 + rg;
                    pout[pxl * 46 + o] = acc[jm][nf][rg] + bias;
                }
            }
        }
    __syncthreads();

    const float AW[9] = {90.50966799187809f, 128.0f, 181.01933598375618f,
                         181.01933598375618f, 256.0f, 362.03867196751236f,
                         362.03867196751236f, 512.0f, 724.0773439350247f};
    const float AH[9] = {181.01933598375618f, 128.0f, 90.50966799187809f,
                         362.03867196751236f, 256.0f, 181.01933598375618f,
                         724.0773439350247f, 512.0f, 362.03867196751236f};
    const float CLIPV = 4.135166556742356f;
    const float IMG = 1600.0f;

    for (int it = t; it < 128 * 9; it += 256) {
        int pxl = it / 9, a = it - pxl * 9;
        int pxg = px0 + pxl;
        if (pxg >= 20000) continue;
        int b = pxg / 2500, rem = pxg % 2500;
        int h = rem / 50, w = rem % 50;

        float tx = pout[pxl * 46 + a * 4 + 0];
        float ty = pout[pxl * 46 + a * 4 + 1];
        float tw = pout[pxl * 46 + a * 4 + 2];
        float th = pout[pxl * 46 + a * 4 + 3];
        float lg = pout[pxl * 46 + 36 + a];

        float s = 1.0f / (1.0f + expf(-lg));

        float cx = ((float)w + 0.5f) * 32.0f;
        float cy = ((float)h + 0.5f) * 32.0f;
        float x1a = cx - 0.5f * AW[a];
        float x2a = cx + 0.5f * AW[a];
        float y1a = cy - 0.5f * AH[a];
        float y2a = cy + 0.5f * AH[a];
        float waf = x2a - x1a;
        float haf = y2a - y1a;
        float cxa = x1a + 0.5f * waf;
        float cya = y1a + 0.5f * haf;

        float twc = tw < CLIPV ? tw : CLIPV;
        float thc = th < CLIPV ? th : CLIPV;
        float pxc = tx * waf + cxa;
        float pyc = ty * haf + cya;
        float pw  = expf(twc) * waf;
        float ph  = expf(thc) * haf;

        float x1 = pxc - 0.5f * pw;
        float y1 = pyc - 0.5f * ph;
        float x2 = pxc + 0.5f * pw;
        float y2 = pyc + 0.5f * ph;
        x1 = fminf(fmaxf(x1, 0.f), IMG);
        y1 = fminf(fmaxf(y1, 0.f), IMG);
        x2 = fminf(fmaxf(x2, 0.f), IMG);
        y2 = fminf(fmaxf(y2, 0.f), IMG);

        float bw = x2 - x1, bh = y2 - y1;
        bool valid = (s >= 0.1f) && (bw > 16.0f) && (bh > 16.0f);
        float m = valid ? s : -1.0f;

        int idx = (h * WDIM + w) * NA + a;
        size_t gi = (size_t)b * NANCH + idx;
        ((float4*)boxes)[gi] = make_float4(x1, y1, x2, y2);
        unsigned int u = __float_as_uint(m);
        unsigned int k32 = (u & 0x80000000u) ? ~u : (u | 0x80000000u);
        keys[gi] = ((unsigned long long)k32 << 15) | (unsigned long long)(32767 - idx);
    }
}

// ---------------- exact stable top-2000: 6x8-bit radix select w/ per-wave hists + bitonic ----------------
__global__ __launch_bounds__(1024) void select_sort_kernel(const unsigned long long* __restrict__ keys,
                                                           const float* __restrict__ boxes,
                                                           float* __restrict__ top_boxes,
                                                           float* __restrict__ top_s) {
    int b = blockIdx.x;
    int t = threadIdx.x;
    int wv = t >> 6;
    const unsigned long long* kb = keys + (size_t)b * NANCH;

    __shared__ unsigned int whist[16][256];
    __shared__ unsigned int hist[256];
    __shared__ int s_chosen, s_rnew;
    __shared__ unsigned int s_cnt;
    __shared__ unsigned long long skeys[2048];

    const int widths[6] = {8, 8, 8, 8, 8, 7};
    unsigned long long prefix = 0;
    int bitsdone = 0;
    int r = PRE_N;

    for (int p = 0; p < 6; ++p) {
        int width = widths[p];
        int bins = 1 << width;
        int shift = 47 - bitsdone - width;
        for (int i = t; i < 16 * 256; i += 1024) ((unsigned int*)whist)[i] = 0;
        __syncthreads();
        for (int i = t; i < NANCH; i += 1024) {
            unsigned long long k = kb[i];
            if ((k >> (47 - bitsdone)) == prefix)
                atomicAdd(&whist[wv][(unsigned)((k >> shift) & (unsigned long long)(bins - 1))], 1u);
        }
        __syncthreads();
        if (t < bins) {
            unsigned int s = 0;
#pragma unroll
            for (int w = 0; w < 16; ++w) s += whist[w][t];
            hist[t] = s;
        }
        __syncthreads();
        if (t == 0) {
            int acc = 0, chosen = 0, rnew = 1;
            for (int d = bins - 1; d >= 0; --d) {
                int hv = (int)hist[d];
                if (acc + hv >= r) { chosen = d; rnew = r - acc; break; }
                acc += hv;
            }
            s_chosen = chosen;
            s_rnew = rnew;
        }
        __syncthreads();
        prefix = (prefix << width) | (unsigned long long)s_chosen;
        bitsdone += width;
        r = s_rnew;
        __syncthreads();
    }
    unsigned long long Kst = prefix;

    if (t == 0) s_cnt = 0;
    __syncthreads();
    for (int i = t; i < NANCH; i += 1024) {
        unsigned long long k = kb[i];
        if (k >= Kst) {
            unsigned int p = atomicAdd(&s_cnt, 1u);
            if (p < 2048) skeys[p] = k;
        }
    }
    __syncthreads();
    unsigned int cnt = s_cnt;
    for (int i = t; i < 2048; i += 1024)
        if (i >= (int)cnt) skeys[i] = 0ull;
    for (int k = 2; k <= 2048; k <<= 1) {
        for (int j = k >> 1; j > 0; j >>= 1) {
            __syncthreads();
            for (int i = t; i < 2048; i += 1024) {
                int l = i ^ j;
                if (l > i) {
                    unsigned long long a = skeys[i], c = skeys[l];
                    bool up = ((i & k) == 0);
                    if (up ? (a < c) : (a > c)) { skeys[i] = c; skeys[l] = a; }
                }
            }
        }
    }
    __syncthreads();
    for (int i = t; i < PRE_N; i += 1024) {
        unsigned long long k = skeys[i];
        unsigned int k32 = (unsigned int)(k >> 15);
        float m = (k32 & 0x80000000u) ? __uint_as_float(k32 & 0x7FFFFFFFu)
                                      : __uint_as_float(~k32);
        unsigned int idx = 32767u - (unsigned int)(k & 32767ull);
        size_t gi = (size_t)b * NANCH + idx;
        top_s[b * PRE_N + i] = m;
        ((float4*)top_boxes)[b * PRE_N + i] = ((const float4*)boxes)[gi];
    }
}

// ---------------- IoU suppression bit-matrix ----------------
__global__ __launch_bounds__(256) void sup_kernel(const float* __restrict__ top_boxes,
                                                  unsigned long long* __restrict__ supm) {
    int blk = blockIdx.x;
    int b = blk / 125;
    int chunk = blk % 125;
    int t = threadIdx.x;

    __shared__ float bx1[PRE_N], by1[PRE_N], bx2[PRE_N], by2[PRE_N];
    for (int i = t; i < PRE_N; i += 256) {
        float4 v = ((const float4*)top_boxes)[b * PRE_N + i];
        bx1[i] = v.x; by1[i] = v.y; bx2[i] = v.z; by2[i] = v.w;
    }
    __syncthreads();

    int wave = t >> 6, lane = t & 63;
    for (int rr = 0; rr < 4; ++rr) {
        int i = chunk * 16 + wave * 4 + rr;
        float ax1 = bx1[i], ay1 = by1[i], ax2 = bx2[i], ay2 = by2[i];
        float aarea = (ax2 - ax1) * (ay2 - ay1);
        for (int jw = 0; jw < 32; ++jw) {
            int j = jw * 64 + lane;
            bool sup = false;
            if (j > i && j < PRE_N) {
                float jx1 = bx1[j], jy1 = by1[j], jx2 = bx2[j], jy2 = by2[j];
                float ix1 = fmaxf(ax1, jx1), iy1 = fmaxf(ay1, jy1);
                float ix2 = fminf(ax2, jx2), iy2 = fminf(ay2, jy2);
                float iw = fmaxf(ix2 - ix1, 0.f);
                float ih = fmaxf(iy2 - iy1, 0.f);
                float inter = iw * ih;
                float barea = (jx2 - jx1) * (jy2 - jy1);
                float iou = inter / (aarea + barea - inter + 1e-9f);
                sup = iou > 0.7f;
            }
            unsigned long long m = __ballot(sup);
            if (lane == 0) supm[((size_t)b * PRE_N + i) * 32 + jw] = m;
        }
    }
}

// ---------------- fused: tiled NMS scan (wave 0) + stable top-100 finalize ----------------
__global__ __launch_bounds__(256) void nms_fin_kernel(const float* __restrict__ top_s,
                                                      const unsigned long long* __restrict__ supm,
                                                      const float* __restrict__ top_boxes,
                                                      float* __restrict__ out) {
    int b = blockIdx.x;
    int t = threadIdx.x;
    __shared__ unsigned int kw[64];
    __shared__ int wpre[65];

    if (t < 64) {
        int lane = t;
        unsigned int alive = 0;
        for (int q = 0; q < 32; ++q) {
            int i = lane * 32 + q;
            if (i < PRE_N && top_s[b * PRE_N + i] > 0.f) alive |= (1u << q);
        }
        const unsigned long long* sm = supm + (size_t)b * PRE_N * 32;
        const unsigned int* sup32 = (const unsigned int*)sm;

        for (int tt = 0; tt < 32; ++tt) {
            unsigned int alo = __shfl(alive, 2 * tt);
            unsigned int ahi = __shfl(alive, 2 * tt + 1);
            unsigned long long talive = (unsigned long long)alo | ((unsigned long long)ahi << 32);
            int i_row = tt * 64 + lane;
            unsigned long long rm = (i_row < PRE_N) ? sm[(size_t)i_row * 32 + tt] : 0ull;

            unsigned long long kept = 0, rem = talive;
            while (rem) {
                int j = __builtin_ctzll(rem);
                kept |= (1ull << j);
                unsigned long long rmj = __shfl(rm, j);
                rem &= ~rmj;
                rem &= ~(1ull << j);
            }

            unsigned int oracc = 0;
            unsigned long long kk = kept;
            while (kk) {
                int j0 = __builtin_ctzll(kk); kk &= kk - 1;
                int j1 = -1, j2 = -1, j3 = -1;
                if (kk) { j1 = __builtin_ctzll(kk); kk &= kk - 1; }
                if (kk) { j2 = __builtin_ctzll(kk); kk &= kk - 1; }
                if (kk) { j3 = __builtin_ctzll(kk); kk &= kk - 1; }
                unsigned int v0 = sup32[(size_t)(tt * 64 + j0) * 64 + lane];
                unsigned int v1 = (j1 >= 0) ? sup32[(size_t)(tt * 64 + j1) * 64 + lane] : 0u;
                unsigned int v2 = (j2 >= 0) ? sup32[(size_t)(tt * 64 + j2) * 64 + lane] : 0u;
                unsigned int v3 = (j3 >= 0) ? sup32[(size_t)(tt * 64 + j3) * 64 + lane] : 0u;
                oracc |= v0 | v1 | v2 | v3;
            }
            alive &= ~oracc;
            if (lane == 2 * tt)     alive = (unsigned int)kept;
            if (lane == 2 * tt + 1) alive = (unsigned int)(kept >> 32);
        }
        kw[lane] = alive;
    }
    __syncthreads();
    if (t == 0) {
        int run = 0;
        for (int w = 0; w < 64; ++w) { wpre[w] = run; run += __popc(kw[w]); }
        wpre[64] = run;
    }
    __syncthreads();
    int total = wpre[64];
    float* out_boxes  = out;
    float* out_scores = out + NB * POST_N * 4;
    for (int i = t; i < PRE_N; i += 256) {
        unsigned int w = kw[i >> 5];
        bool kept = (w >> (i & 31)) & 1u;
        int rk = wpre[i >> 5] + __popc(w & ((1u << (i & 31)) - 1u));
        int pos = kept ? rk : total + (i - rk);
        if (pos < POST_N) {
            out_scores[b * POST_N + pos] = kept ? top_s[b * PRE_N + i] : -1.0f;
            ((float4*)out_boxes)[b * POST_N + pos] = ((const float4*)top_boxes)[b * PRE_N + i];
        }
    }
}

// ---------------- launch ----------------
extern "C" void kernel_launch(void* const* d_in, const int* in_sizes, int n_in,
                              void* d_out, int out_size, void* d_ws, size_t ws_size,
                              hipStream_t stream) {
    const float* features = (const float*)d_in[0];
    const float* W1 = (const float*)d_in[1];
    const float* b1 = (const float*)d_in[2];
    const float* W2 = (const float*)d_in[3];
    const float* b2 = (const float*)d_in[4];
    const float* W3 = (const float*)d_in[5];
    const float* b3 = (const float*)d_in[6];
    float* out = (float*)d_out;
    char* ws = (char*)d_ws;

    unsigned short* Tph = (unsigned short*)(ws + OFF_TPH);
    unsigned short* Tpl = (unsigned short*)(ws + OFF_TPL);
    float* boxes   = (float*)(ws + OFF_BOXES);
    unsigned long long* keys = (unsigned long long*)(ws + OFF_KEYS);
    float* top_boxes = (float*)(ws + OFF_TBOX);
    float* top_s     = (float*)(ws + OFF_TS);
    unsigned long long* supm = (unsigned long long*)(ws + OFF_SUP);
    unsigned short* FPh = (unsigned short*)(ws + OFF_PH);
    unsigned short* FPl = (unsigned short*)(ws + OFF_PL);
    unsigned short* WPh = (unsigned short*)(ws + OFF_WH);
    unsigned short* WPl = (unsigned short*)(ws + OFF_WL);

    prep_all<<<6080, 256, 0, stream>>>(features, W1, FPh, FPl, WPh, WPl);
    conv_mfma<<<704, 256, 0, stream>>>(FPh, FPl, WPh, WPl, b1, Tph, Tpl);
    proj_decode_mfma<<<157, 256, 0, stream>>>(Tph, Tpl, W2, b2, W3, b3, boxes, keys);
    select_sort_kernel<<<NB, 1024, 0, stream>>>(keys, boxes, top_boxes, top_s);
    sup_kernel<<<NB * 125, 256, 0, stream>>>(top_boxes, supm);
    nms_fin_kernel<<<NB, 256, 0, stream>>>(top_s, supm, top_boxes, out);
}